// Round 5
// baseline (1719.475 us; speedup 1.0000x reference)
//
#include <hip/hip_runtime.h>
#include <cstdint>
#include <cstddef>

#define T_ 512
#define B_ 128
#define D_ 256
#define H_ 512
#define C_ 10

typedef float  f32x4 __attribute__((ext_vector_type(4)));
typedef short  s16x8 __attribute__((ext_vector_type(8)));
typedef _Float16 v8h __attribute__((ext_vector_type(8)));
typedef _Float16 v2h __attribute__((ext_vector_type(2)));

static __device__ __forceinline__ unsigned short f2bf(float f) {
    unsigned u = __builtin_bit_cast(unsigned, f);
    unsigned r = u + 0x7FFFu + ((u >> 16) & 1u);   // round-to-nearest-even
    return (unsigned short)(r >> 16);
}

// ---------------------------------------------------------------------------
// Prep 0: W_hx [256,512] f32 -> W_hx^T [512,256] bf16 (B-operand for k_gemm1)
// ---------------------------------------------------------------------------
__global__ void k_whxT(const float* __restrict__ Whx, unsigned short* __restrict__ WhxT) {
    int idx = blockIdx.x * 256 + threadIdx.x;
    int n = idx >> 8;
    int k = idx & 255;
    WhxT[n * 256 + k] = f2bf(Whx[k * 512 + n]);
}

// ---------------------------------------------------------------------------
// Prep 1: W_hh [512,512] f32 -> Wf: f16 MFMA B-fragments.
// Wf entry gid = ((w*16 + s)*8 + nb)*64 + l holds 8 f16:
//   B[k = 32s + (l>>4)*8 + j][col = 128w + 16nb + (l&15)], j = 0..7
// ---------------------------------------------------------------------------
__global__ void k_wfrag(const float* __restrict__ Whh, _Float16* __restrict__ Wf) {
    int gid = blockIdx.x * 256 + threadIdx.x;   // 32768 total
    int l   = gid & 63;
    int grp = gid >> 6;                          // ((w*16+s)*8+nb)
    int nb  = grp & 7;
    int s   = (grp >> 3) & 15;
    int w   = grp >> 7;
    int col = w * 128 + nb * 16 + (l & 15);
    int k0  = s * 32 + (l >> 4) * 8;
    v8h v;
#pragma unroll
    for (int j = 0; j < 8; ++j)
        v[j] = (_Float16)Whh[(size_t)(k0 + j) * 512 + col];
    *(v8h*)(Wf + (size_t)gid * 8) = v;
}

// ---------------------------------------------------------------------------
// Phase 1: Z = x @ W_hx + b_h, written directly in k_rnn's Zr layout:
// Zr block (t, cu, w) = 4096 B at ((t*8+cu)*4+w)*4096, layout [g 0..3][m 0..63][q 0..7] f16,
// value(q) = z[t][16cu + (m>>4)*4 + (q&3)][128w + 16*(2g + (q>>2)) + (m&15)].
// GEMM: 128x128 tile (mt = t, nt = w), 4 waves, mfma_f32_16x16x32_bf16.
// ---------------------------------------------------------------------------
__global__ void __launch_bounds__(256) k_gemm1(const float* __restrict__ x,
                                               const unsigned short* __restrict__ WhxT,
                                               const float* __restrict__ bh,
                                               char* __restrict__ Zr) {
    __shared__ char smem[32768];
    unsigned short* Asm = (unsigned short*)smem;          // [128][32] bf16 (8 KiB)
    unsigned short* Bsm = (unsigned short*)(smem + 8192); // [128][32] bf16 (8 KiB)

    const int tid = threadIdx.x;
    const int bid = blockIdx.x;
    const int nt = bid & 3, mt = bid >> 2;
    const int r0 = mt * 128, n0 = nt * 128;
    const int w  = tid >> 6, l = tid & 63;
    const int wm = (w >> 1) * 64, wn = (w & 1) * 64;
    const int lr = l & 15, lk = (l >> 4) * 8;

    const int arow = tid >> 2, akc = (tid & 3) * 8;
    const int bcol = tid >> 1, bkc = (tid & 1) * 16;

    f32x4 acc[4][4] = {};

    for (int kk = 0; kk < 256; kk += 32) {
#pragma unroll
        for (int half = 0; half < 2; ++half) {
            const int r = arow + half * 64;
            const float* ap = x + (size_t)(r0 + r) * 256 + kk + akc;
            float4 f0 = *(const float4*)ap;
            float4 f1 = *(const float4*)(ap + 4);
            uint4 av;
            av.x = (unsigned)f2bf(f0.x) | ((unsigned)f2bf(f0.y) << 16);
            av.y = (unsigned)f2bf(f0.z) | ((unsigned)f2bf(f0.w) << 16);
            av.z = (unsigned)f2bf(f1.x) | ((unsigned)f2bf(f1.y) << 16);
            av.w = (unsigned)f2bf(f1.z) | ((unsigned)f2bf(f1.w) << 16);
            *(uint4*)&Asm[r * 32 + akc] = av;
        }
        const unsigned short* bsrc = WhxT + (size_t)(n0 + bcol) * 256 + kk + bkc;
        uint4 bv0 = *(const uint4*)bsrc;
        uint4 bv1 = *(const uint4*)(bsrc + 8);
        *(uint4*)&Bsm[bcol * 32 + bkc] = bv0;
        *(uint4*)&Bsm[bcol * 32 + bkc + 8] = bv1;
        __syncthreads();

        s16x8 af[4], bf[4];
#pragma unroll
        for (int mi = 0; mi < 4; ++mi)
            af[mi] = *(const s16x8*)&Asm[(wm + mi * 16 + lr) * 32 + lk];
#pragma unroll
        for (int ni = 0; ni < 4; ++ni)
            bf[ni] = *(const s16x8*)&Bsm[(wn + ni * 16 + lr) * 32 + lk];
#pragma unroll
        for (int mi = 0; mi < 4; ++mi)
#pragma unroll
            for (int ni = 0; ni < 4; ++ni)
                acc[mi][ni] = __builtin_amdgcn_mfma_f32_16x16x32_bf16(af[mi], bf[ni], acc[mi][ni], 0, 0, 0);
        __syncthreads();
    }

    // ---- epilogue: stage (z + bh) as f16 into Szr (alias of smem), then coalesced write ----
    _Float16* Szr = (_Float16*)smem;   // [cu 0..7][g 0..3][m 0..63][q 0..7] = 32 KiB
#pragma unroll
    for (int mi = 0; mi < 4; ++mi)
#pragma unroll
        for (int ni = 0; ni < 4; ++ni) {
            const int col_l = wn + ni * 16 + lr;          // 0..127
            const float bhv = bh[n0 + col_l];
            const int g   = (col_l >> 5) & 3;
            const int qhi = ((col_l >> 4) & 1) * 4;
#pragma unroll
            for (int e = 0; e < 4; ++e) {
                const int b   = wm + mi * 16 + (l >> 4) * 4 + e;   // 0..127
                const int cu  = b >> 4;
                const int m_r = ((b & 15) >> 2) * 16 + lr;
                Szr[((cu * 4 + g) * 64 + m_r) * 8 + qhi + e] = (_Float16)(acc[mi][ni][e] + bhv);
            }
        }
    __syncthreads();
    {
        const uint4* srcv = (const uint4*)smem;
#pragma unroll
        for (int i = 0; i < 8; ++i) {
            const int o   = tid * 128 + i * 16;   // byte offset in Szr
            const int cuo = o >> 12;
            char* dst = Zr + ((size_t)((mt * 8 + cuo) * 4 + nt)) * 4096 + (o & 4095);
            *(uint4*)dst = srcv[o >> 4];
        }
    }
}

// ---------------------------------------------------------------------------
// Phase 2: MFMA recurrence. 8 WGs x 256 threads (4 waves, 1/SIMD).
// WG cu owns batches [16cu,16cu+16); wave w owns cols [128w,128w+128).
// Per step: h_new[16,512] = tanh(h[16,512] @ W_hh + z). K=512 = 16 slices of 32.
//   B slices 0..10 in VGPRs (352), slice 11 from L1/L2 per step, 12..15 in LDS.
//   h in LDS in exact A-fragment layout -> conflict-free ds_read_b128.
// Two barriers/step; z prefetched one step ahead (4x dwordx4).
// ---------------------------------------------------------------------------
__global__ void __launch_bounds__(256, 1) k_rnn(const _Float16* __restrict__ Wf,
                                                const char* __restrict__ Zr,
                                                float* __restrict__ hf) {
    __shared__ _Float16 Blds[4 * 4 * 8 * 512];   // [w][s-12][nb][512 f16] = 128 KiB
    __shared__ _Float16 h_a[16 * 512];           // [s][l*8+j] = 16 KiB

    const int tid = threadIdx.x;
    const int cu  = blockIdx.x;
    const int w   = tid >> 6;
    const int l   = tid & 63;

    // ---- stationary B fragments: slices 0..10 in registers ----
    v8h Br[11][8];
#pragma unroll
    for (int s = 0; s < 11; ++s)
#pragma unroll
        for (int nb = 0; nb < 8; ++nb)
            Br[s][nb] = *(const v8h*)(Wf + (size_t)(((w * 16 + s) * 8 + nb) * 64 + l) * 8);

    // ---- slices 12..15 -> LDS ----
#pragma unroll
    for (int s4 = 0; s4 < 4; ++s4)
#pragma unroll
        for (int nb = 0; nb < 8; ++nb)
            *(v8h*)&Blds[(((w * 4 + s4) * 8 + nb) * 512) + l * 8] =
                *(const v8h*)(Wf + (size_t)(((w * 16 + 12 + s4) * 8 + nb) * 64 + l) * 8);

    // ---- h0 = 0 ----
#pragma unroll
    for (int i = 0; i < 4; ++i)
        ((uint4*)h_a)[i * 256 + tid] = uint4{0, 0, 0, 0};
    __syncthreads();

    // ---- z prefetch for t=0 ----
    uint4 z4[4];
    {
        const uint4* zb = (const uint4*)(Zr + ((size_t)cu * 4 + w) * 4096);
#pragma unroll
        for (int g = 0; g < 4; ++g) z4[g] = zb[g * 64 + l];
    }

    f32x4 C[8];
    for (int t = 0; t < T_; ++t) {
        __syncthreads();                       // h_a for step t visible

        // slice-11 B from global (L1/L2-resident; same addresses every step)
        v8h Bg[8];
#pragma unroll
        for (int nb = 0; nb < 8; ++nb)
            Bg[nb] = *(const v8h*)(Wf + (size_t)(((w * 16 + 11) * 8 + nb) * 64 + l) * 8);

        // ---- MFMA over 16 K-slices ----
        v8h A = *(const v8h*)&h_a[l * 8];      // s = 0
#pragma unroll
        for (int nb = 0; nb < 8; ++nb)
            C[nb] = __builtin_amdgcn_mfma_f32_16x16x32_f16(A, Br[0][nb], f32x4{0.f, 0.f, 0.f, 0.f}, 0, 0, 0);
#pragma unroll
        for (int s = 1; s < 11; ++s) {
            A = *(const v8h*)&h_a[s * 512 + l * 8];
#pragma unroll
            for (int nb = 0; nb < 8; ++nb)
                C[nb] = __builtin_amdgcn_mfma_f32_16x16x32_f16(A, Br[s][nb], C[nb], 0, 0, 0);
        }
        A = *(const v8h*)&h_a[11 * 512 + l * 8];
#pragma unroll
        for (int nb = 0; nb < 8; ++nb)
            C[nb] = __builtin_amdgcn_mfma_f32_16x16x32_f16(A, Bg[nb], C[nb], 0, 0, 0);
#pragma unroll
        for (int s4 = 0; s4 < 4; ++s4) {
            A = *(const v8h*)&h_a[(12 + s4) * 512 + l * 8];
#pragma unroll
            for (int nb = 0; nb < 8; ++nb) {
                v8h Bl = *(const v8h*)&Blds[(((w * 4 + s4) * 8 + nb) * 512) + l * 8];
                C[nb] = __builtin_amdgcn_mfma_f32_16x16x32_f16(A, Bl, C[nb], 0, 0, 0);
            }
        }
        __syncthreads();                       // all h_a reads done; safe to overwrite

        // ---- epilogue: z + tanh -> scatter h_new into A-fragment layout ----
#pragma unroll
        for (int nb = 0; nb < 8; ++nb) {
            const int col = w * 128 + nb * 16 + (l & 15);
            const int sA  = col >> 5;
            const int hi2 = (col >> 3) & 3;
            const int j   = col & 7;
            const unsigned zw0 = (nb & 1) ? z4[nb >> 1].z : z4[nb >> 1].x;
            const unsigned zw1 = (nb & 1) ? z4[nb >> 1].w : z4[nb >> 1].y;
#pragma unroll
            for (int e = 0; e < 4; ++e) {
                const unsigned zw = (e < 2) ? zw0 : zw1;
                const _Float16 zh = __builtin_bit_cast(v2h, zw)[e & 1];
                const float sv = C[nb][e] + (float)zh;
                const float ex = __expf(2.0f * sv);
                const float hv = 1.0f - 2.0f * __builtin_amdgcn_rcpf(ex + 1.0f);
                h_a[sA * 512 + hi2 * 128 + ((l >> 4) * 4 + e) * 8 + j] = (_Float16)hv;
                if (t == T_ - 1)
                    hf[((size_t)16 * cu + (l >> 4) * 4 + e) * 512 + col] = hv;
            }
        }

        // ---- prefetch next step's z ----
        if (t + 1 < T_) {
            const uint4* zb = (const uint4*)(Zr + (((size_t)(t + 1) * 8 + cu) * 4 + w) * 4096);
#pragma unroll
            for (int g = 0; g < 4; ++g) z4[g] = zb[g * 64 + l];
        }
    }
}

// ---------------------------------------------------------------------------
// Phase 3: out = h_final @ W_ph + b_p   [128,512]@[512,10]
// ---------------------------------------------------------------------------
__global__ void k_out(const float* __restrict__ hf, const float* __restrict__ Wph,
                      const float* __restrict__ bp, float* __restrict__ out) {
    __shared__ float red[160];
    int b = blockIdx.x, t = threadIdx.x;
    if (t < 160) {
        int c = t >> 4, ks = (t & 15) * 32;
        float s = 0.f;
        for (int u = 0; u < 32; ++u)
            s += hf[b * H_ + ks + u] * Wph[(ks + u) * C_ + c];
        red[t] = s;
    }
    __syncthreads();
    if (t < C_) {
        float s = bp[t];
        for (int i = 0; i < 16; ++i) s += red[t * 16 + i];
        out[b * C_ + t] = s;
    }
}

// ---------------------------------------------------------------------------
extern "C" void kernel_launch(void* const* d_in, const int* in_sizes, int n_in,
                              void* d_out, int out_size, void* d_ws, size_t ws_size,
                              hipStream_t stream) {
    const float* x   = (const float*)d_in[0];   // [512,128,256]
    const float* Whx = (const float*)d_in[1];   // [256,512]
    const float* Whh = (const float*)d_in[2];   // [512,512]
    const float* Wph = (const float*)d_in[3];   // [512,10]
    const float* bh  = (const float*)d_in[4];   // [512]
    const float* bp  = (const float*)d_in[5];   // [10]
    float* out = (float*)d_out;                 // [128,10] f32

    char* ws = (char*)d_ws;
    unsigned short* WhxT = (unsigned short*)(ws);                    // 256 KiB
    _Float16*       Wf   = (_Float16*)(ws + 262144);                 // 512 KiB
    char*           Zr   = ws + 786432;                              // 64 MiB
    float*          hf   = (float*)(ws + 786432 + 67108864);         // 256 KiB

    hipLaunchKernelGGL(k_whxT,  dim3(512),  dim3(256), 0, stream, Whx, WhxT);
    hipLaunchKernelGGL(k_wfrag, dim3(128),  dim3(256), 0, stream, Whh, Wf);
    hipLaunchKernelGGL(k_gemm1, dim3(2048), dim3(256), 0, stream, x, WhxT, bh, Zr);
    hipLaunchKernelGGL(k_rnn,   dim3(8),    dim3(256), 0, stream, Wf, Zr, hf);
    hipLaunchKernelGGL(k_out,   dim3(128),  dim3(256), 0, stream, hf, Wph, bp, out);
}